// Round 5
// baseline (730.757 us; speedup 1.0000x reference)
//
#include <hip/hip_runtime.h>
#include <hip/hip_bf16.h>

// RGCN layer, input-space aggregation:
//   counting-sort edges by key = dst*8+etype (scatter packs src|rel|ld into one int);
//   x pre-converted to bf16 (halves gather bytes); fused kernel does edge-parallel
//   aggregation with MANUAL 8-edge batches (8 independent row loads in flight/wave)
//   into an f32 LDS tile via ds_add_f32, then mean-scale + bf16, then one MFMA GEMM
//   K = 8*128+128 vs [W_0;..;W_7;root] (W_r = comp@basis), bias+PReLU epilogue.

#define N_NODES 50000
#define N_EDGES 800000
#define N_REL   8
#define CH      128
#define KTOT    1152                       // 8*128 + 128 (root)
#define NSEG    (N_NODES * N_REL)          // 400000
#define DT      16                         // dst rows per fused block
#define SCAN_BLK 1024
#define NSCAN   ((NSEG + SCAN_BLK - 1) / SCAN_BLK)  // 391
#define FSTRIDE 1156                       // f32 accumulator row stride (pad 4)
#define BSTRIDE 1160                       // bf16 row stride; 2320B/16 = 145 ≡ 1 mod 8
#define EB      8                          // edges per wave per batch

typedef __attribute__((ext_vector_type(8))) short bf16x8;
typedef __attribute__((ext_vector_type(4))) float f32x4;

// WcatT[o][k]: B^T view of the [KTOT x CH] weight stack, bf16.
__global__ void k_build_w(const float* __restrict__ basis, const float* __restrict__ comp,
                          const float* __restrict__ root, __hip_bfloat16* __restrict__ WcatT) {
  int idx = blockIdx.x * 256 + threadIdx.x;
  if (idx >= CH * KTOT) return;
  int o = idx / KTOT, k = idx % KTOT;
  float v;
  if (k < N_REL * CH) {
    int r = k >> 7, i = k & (CH - 1);
    float acc = 0.f;
#pragma unroll
    for (int b = 0; b < 8; ++b) acc += comp[r * 8 + b] * basis[(b * CH + i) * CH + o];
    v = acc;
  } else {
    int i = k - N_REL * CH;
    v = root[i * CH + o];
  }
  WcatT[(size_t)o * KTOT + k] = __float2bfloat16(v);
}

// x (f32) -> xb (bf16 packed pairs), one uint = 2 channels.
__global__ void k_xbf16(const float* __restrict__ x, unsigned int* __restrict__ xb) {
  int idx = blockIdx.x * 256 + threadIdx.x;          // one thread = 4 channels
  if (idx >= N_NODES * CH / 4) return;
  const float4 v = *reinterpret_cast<const float4*>(x + (size_t)idx * 4);
  __hip_bfloat16 h0 = __float2bfloat16(v.x), h1 = __float2bfloat16(v.y);
  __hip_bfloat16 h2 = __float2bfloat16(v.z), h3 = __float2bfloat16(v.w);
  unsigned int u0 = *(unsigned short*)&h0 | ((unsigned int)*(unsigned short*)&h1 << 16);
  unsigned int u1 = *(unsigned short*)&h2 | ((unsigned int)*(unsigned short*)&h3 << 16);
  xb[(size_t)idx * 2]     = u0;
  xb[(size_t)idx * 2 + 1] = u1;
}

__global__ void k_hist(const int* __restrict__ dst, const int* __restrict__ et,
                       int* __restrict__ hist) {
  int e = blockIdx.x * 256 + threadIdx.x;
  if (e < N_EDGES) atomicAdd(&hist[dst[e] * N_REL + et[e]], 1);
}

__global__ void k_scan1(const int* __restrict__ hist, int* __restrict__ off,
                        int* __restrict__ bsum) {
  __shared__ int sd[256];
  int t = threadIdx.x, b = blockIdx.x;
  int base = b * SCAN_BLK + t * 4;
  int v[4]; int s = 0;
#pragma unroll
  for (int j = 0; j < 4; ++j) { int i = base + j; v[j] = (i < NSEG) ? hist[i] : 0; s += v[j]; }
  sd[t] = s; __syncthreads();
  for (int o = 1; o < 256; o <<= 1) {
    int add = (t >= o) ? sd[t - o] : 0; __syncthreads();
    sd[t] += add; __syncthreads();
  }
  int excl = sd[t] - s;
  int run = excl;
#pragma unroll
  for (int j = 0; j < 4; ++j) { int i = base + j; if (i < NSEG) off[i] = run; run += v[j]; }
  if (t == 255) bsum[b] = sd[255];
}

__global__ void k_scan2(int* __restrict__ bsum) {
  __shared__ int sd[512];
  int t = threadIdx.x;
  int v = (t < NSCAN) ? bsum[t] : 0;
  sd[t] = v; __syncthreads();
  for (int o = 1; o < 512; o <<= 1) {
    int add = (t >= o) ? sd[t - o] : 0; __syncthreads();
    sd[t] += add; __syncthreads();
  }
  int excl = (t == 0) ? 0 : sd[t - 1];
  if (t < NSCAN) bsum[t] = excl;
}

__global__ void k_scan3(int* __restrict__ off, const int* __restrict__ bsum) {
  int t = threadIdx.x, b = blockIdx.x;
  int add = bsum[b];
  int base = b * SCAN_BLK + t * 4;
#pragma unroll
  for (int j = 0; j < 4; ++j) { int i = base + j; if (i < NSEG) off[i] += add; }
  if (b == 0 && t == 0) off[NSEG] = N_EDGES;
}

// Packs src | rel<<20 | (dst&15)<<23 so the fused kernel gets everything in one int.
__global__ void k_scatter(const int* __restrict__ src, const int* __restrict__ dst,
                          const int* __restrict__ et, const int* __restrict__ off,
                          int* __restrict__ cursor, int* __restrict__ srcPk) {
  int e = blockIdx.x * 256 + threadIdx.x;
  if (e >= N_EDGES) return;
  int d = dst[e], r = et[e];
  int key = d * N_REL + r;
  int pos = off[key] + atomicAdd(&cursor[key], 1);
  srcPk[pos] = src[e] | (r << 20) | ((d & 15) << 23);
}

__global__ __launch_bounds__(512)
void k_fused(const float* __restrict__ x, const unsigned int* __restrict__ xb,
             const int* __restrict__ off, const int* __restrict__ srcPk,
             const __hip_bfloat16* __restrict__ WcatT,
             const float* __restrict__ bias, const float* __restrict__ alpha,
             float* __restrict__ out) {
  __shared__ float Af[DT * FSTRIDE];       // 73,984 B; bf16 A reuses its low half
  __shared__ float invc[DT * N_REL];
  int tid = threadIdx.x;
  int wave = tid >> 6, lane = tid & 63;
  int dstBase = blockIdx.x * DT;
  int seg0 = dstBase * N_REL;

  // ---- pre-pass: zero agg region; copy root rows (f32 x); per-segment 1/cnt ----
  for (int i = tid; i < DT * 1024; i += 512)
    Af[(i >> 10) * FSTRIDE + (i & 1023)] = 0.f;
  {
    int ld = tid >> 5, c4 = (tid & 31) * 4;
    const float4 v = *reinterpret_cast<const float4*>(x + (size_t)(dstBase + ld) * CH + c4);
    float* p = &Af[ld * FSTRIDE + 1024 + c4];
    p[0] = v.x; p[1] = v.y; p[2] = v.z; p[3] = v.w;
  }
  if (tid < DT * N_REL) {
    int c = off[seg0 + tid + 1] - off[seg0 + tid];
    invc[tid] = (c > 0) ? 1.0f / (float)c : 0.0f;
  }
  int ebeg = off[seg0];
  int eend = off[seg0 + DT * N_REL];
  __syncthreads();

  // ---- edge-parallel accumulation, manual EB-batch: 8 independent row loads ----
  for (int base = ebeg + wave * EB; base < eend; base += 8 * EB) {
    int pk[EB];
#pragma unroll
    for (int j = 0; j < EB; ++j) {
      int e = base + j;
      pk[j] = srcPk[(e < eend) ? e : ebeg];          // clamp to a valid edge
    }
    unsigned int u[EB];
#pragma unroll
    for (int j = 0; j < EB; ++j)
      u[j] = xb[(size_t)(pk[j] & 0xFFFFF) * 64 + lane];   // 256B coalesced bf16 row
#pragma unroll
    for (int j = 0; j < EB; ++j) {
      if (base + j < eend) {                         // wave-uniform guard
        int r = (pk[j] >> 20) & 7, ld = (pk[j] >> 23) & 15;
        float* row = &Af[ld * FSTRIDE + r * CH + lane * 2];
        unsafeAtomicAdd(row,     __uint_as_float(u[j] << 16));
        unsafeAtomicAdd(row + 1, __uint_as_float(u[j] & 0xffff0000u));
      }
    }
  }
  __syncthreads();

  // ---- scale (mean) + in-place f32 -> bf16, register-staged ----
  float st[36];                            // DT*KTOT/512 == 36 exactly
#pragma unroll
  for (int j = 0; j < 36; ++j) {
    int idx = tid + j * 512;
    int ld = idx / KTOT, k = idx - ld * KTOT;
    float v = Af[ld * FSTRIDE + k];
    if (k < N_REL * CH) v *= invc[(ld << 3) + (k >> 7)];
    st[j] = v;
  }
  __syncthreads();
  __hip_bfloat16* B16 = reinterpret_cast<__hip_bfloat16*>(Af);
#pragma unroll
  for (int j = 0; j < 36; ++j) {
    int idx = tid + j * 512;
    int ld = idx / KTOT, k = idx - ld * KTOT;
    B16[ld * BSTRIDE + k] = __float2bfloat16(st[j]);
  }
  __syncthreads();

  // ---- phase B: D[16x16] per wave over K=1152; wave w -> cols [16w,16w+16) ----
  int r16 = lane & 15, g = lane >> 4;
  f32x4 acc = {0.f, 0.f, 0.f, 0.f};
  const short* Wt = reinterpret_cast<const short*>(WcatT) + (size_t)(wave * 16 + r16) * KTOT;
  const short* Arow = reinterpret_cast<const short*>(B16) + r16 * BSTRIDE;
  for (int kk = 0; kk < KTOT / 32; ++kk) {
    int kb = kk * 32 + g * 8;
    bf16x8 af = *reinterpret_cast<const bf16x8*>(Arow + kb);
    bf16x8 bw = *reinterpret_cast<const bf16x8*>(Wt + kb);
    acc = __builtin_amdgcn_mfma_f32_16x16x32_bf16(af, bw, acc, 0, 0, 0);
  }

  int col = wave * 16 + r16;
  float bi = bias[col], al = alpha[col];
#pragma unroll
  for (int rg = 0; rg < 4; ++rg) {
    int row = g * 4 + rg;
    float v = acc[rg] + bi;
    v = (v >= 0.f) ? v : al * v;
    out[(size_t)(dstBase + row) * CH + col] = v;
  }
}

extern "C" void kernel_launch(void* const* d_in, const int* in_sizes, int n_in,
                              void* d_out, int out_size, void* d_ws, size_t ws_size,
                              hipStream_t stream) {
  const float* x     = (const float*)d_in[0];
  const int*   ei    = (const int*)d_in[1];
  const int*   etype = (const int*)d_in[2];
  const float* basis = (const float*)d_in[3];
  const float* comp  = (const float*)d_in[4];
  const float* root  = (const float*)d_in[5];
  const float* bias  = (const float*)d_in[6];
  const float* alpha = (const float*)d_in[7];
  const int* src = ei;
  const int* dst = ei + N_EDGES;
  float* out = (float*)d_out;

  char* ws = (char*)d_ws;
  size_t p = 0;
  auto alloc = [&](size_t bytes) {
    void* q = ws + p;
    p = (p + bytes + 255) & ~(size_t)255;
    return q;
  };
  __hip_bfloat16* WcatT = (__hip_bfloat16*)alloc((size_t)CH * KTOT * sizeof(__hip_bfloat16));
  int* off    = (int*)alloc((size_t)(NSEG + 1) * sizeof(int));
  int* hist   = (int*)alloc((size_t)NSEG * sizeof(int));
  int* cursor = (int*)alloc((size_t)NSEG * sizeof(int));
  int* bsum   = (int*)alloc((size_t)NSCAN * sizeof(int));
  int* srcPk  = (int*)alloc((size_t)N_EDGES * sizeof(int));
  unsigned int* xb = (unsigned int*)alloc((size_t)N_NODES * CH / 2 * sizeof(unsigned int));

  hipMemsetAsync(hist, 0, (size_t)NSEG * sizeof(int), stream);
  hipMemsetAsync(cursor, 0, (size_t)NSEG * sizeof(int), stream);
  k_build_w<<<(CH * KTOT + 255) / 256, 256, 0, stream>>>(basis, comp, root, WcatT);
  k_xbf16<<<(N_NODES * CH / 4 + 255) / 256, 256, 0, stream>>>(x, xb);
  k_hist<<<(N_EDGES + 255) / 256, 256, 0, stream>>>(dst, etype, hist);
  k_scan1<<<NSCAN, 256, 0, stream>>>(hist, off, bsum);
  k_scan2<<<1, 512, 0, stream>>>(bsum);
  k_scan3<<<NSCAN, 256, 0, stream>>>(off, bsum);
  k_scatter<<<(N_EDGES + 255) / 256, 256, 0, stream>>>(src, dst, etype, off, cursor, srcPk);
  k_fused<<<N_NODES / DT, 512, 0, stream>>>(x, xb, off, srcPk, WcatT, bias, alpha, out);
}

// Round 6
// 253.160 us; speedup vs baseline: 2.8865x; 2.8865x over previous
//
#include <hip/hip_runtime.h>
#include <hip/hip_bf16.h>

// RGCN layer, input-space aggregation, NO LDS atomics:
//   counting-sort edges by key = dst*8+etype (scatter bumps off[] itself; post-
//   scatter off[k] = segment END). Fused kernel: each wave owns 2 dst rows'
//   contiguous edge range; 8-edge batches (1 desc load + 8 independent bf16 row
//   gathers), REGISTER accumulation, flush once per sorted run with a plain
//   conflict-free ds_write (mean-scale + bf16 pack at flush). Then one MFMA GEMM
//   K = 8*128+128 vs [W_0;..;W_7;root] (W_r = comp@basis), bias+PReLU epilogue.

#define N_NODES 50000
#define N_EDGES 800000
#define N_REL   8
#define CH      128
#define KTOT    1152                       // 8*128 + 128 (root)
#define NSEG    (N_NODES * N_REL)          // 400000
#define DT      16                         // dst rows per fused block
#define SCAN_BLK 1024
#define NSCAN   ((NSEG + SCAN_BLK - 1) / SCAN_BLK)  // 391
#define BSTRIDE 1160                       // bf16 row stride; 2320B/16 = 145 ≡ 1 mod 8

typedef __attribute__((ext_vector_type(8))) short bf16x8;
typedef __attribute__((ext_vector_type(4))) float f32x4;

// WcatT[o][k]: B^T view of the [KTOT x CH] weight stack, bf16.
__global__ void k_build_w(const float* __restrict__ basis, const float* __restrict__ comp,
                          const float* __restrict__ root, __hip_bfloat16* __restrict__ WcatT) {
  int idx = blockIdx.x * 256 + threadIdx.x;
  if (idx >= CH * KTOT) return;
  int o = idx / KTOT, k = idx % KTOT;
  float v;
  if (k < N_REL * CH) {
    int r = k >> 7, i = k & (CH - 1);
    float acc = 0.f;
#pragma unroll
    for (int b = 0; b < 8; ++b) acc += comp[r * 8 + b] * basis[(b * CH + i) * CH + o];
    v = acc;
  } else {
    int i = k - N_REL * CH;
    v = root[i * CH + o];
  }
  WcatT[(size_t)o * KTOT + k] = __float2bfloat16(v);
}

// x (f32) -> xb (bf16 packed pairs), one uint = 2 channels.
__global__ void k_xbf16(const float* __restrict__ x, unsigned int* __restrict__ xb) {
  int idx = blockIdx.x * 256 + threadIdx.x;          // one thread = 4 channels
  if (idx >= N_NODES * CH / 4) return;
  const float4 v = *reinterpret_cast<const float4*>(x + (size_t)idx * 4);
  __hip_bfloat16 h0 = __float2bfloat16(v.x), h1 = __float2bfloat16(v.y);
  __hip_bfloat16 h2 = __float2bfloat16(v.z), h3 = __float2bfloat16(v.w);
  unsigned int u0 = *(unsigned short*)&h0 | ((unsigned int)*(unsigned short*)&h1 << 16);
  unsigned int u1 = *(unsigned short*)&h2 | ((unsigned int)*(unsigned short*)&h3 << 16);
  xb[(size_t)idx * 2]     = u0;
  xb[(size_t)idx * 2 + 1] = u1;
}

__global__ void k_hist(const int* __restrict__ dst, const int* __restrict__ et,
                       int* __restrict__ hist) {
  int e = blockIdx.x * 256 + threadIdx.x;
  if (e < N_EDGES) atomicAdd(&hist[dst[e] * N_REL + et[e]], 1);
}

__global__ void k_scan1(const int* __restrict__ hist, int* __restrict__ off,
                        int* __restrict__ bsum) {
  __shared__ int sd[256];
  int t = threadIdx.x, b = blockIdx.x;
  int base = b * SCAN_BLK + t * 4;
  int v[4]; int s = 0;
#pragma unroll
  for (int j = 0; j < 4; ++j) { int i = base + j; v[j] = (i < NSEG) ? hist[i] : 0; s += v[j]; }
  sd[t] = s; __syncthreads();
  for (int o = 1; o < 256; o <<= 1) {
    int add = (t >= o) ? sd[t - o] : 0; __syncthreads();
    sd[t] += add; __syncthreads();
  }
  int excl = sd[t] - s;
  int run = excl;
#pragma unroll
  for (int j = 0; j < 4; ++j) { int i = base + j; if (i < NSEG) off[i] = run; run += v[j]; }
  if (t == 255) bsum[b] = sd[255];
}

__global__ void k_scan2(int* __restrict__ bsum) {
  __shared__ int sd[512];
  int t = threadIdx.x;
  int v = (t < NSCAN) ? bsum[t] : 0;
  sd[t] = v; __syncthreads();
  for (int o = 1; o < 512; o <<= 1) {
    int add = (t >= o) ? sd[t - o] : 0; __syncthreads();
    sd[t] += add; __syncthreads();
  }
  int excl = (t == 0) ? 0 : sd[t - 1];
  if (t < NSCAN) bsum[t] = excl;
}

__global__ void k_scan3(int* __restrict__ off, const int* __restrict__ bsum) {
  int t = threadIdx.x, b = blockIdx.x;
  int add = bsum[b];
  int base = b * SCAN_BLK + t * 4;
#pragma unroll
  for (int j = 0; j < 4; ++j) { int i = base + j; if (i < NSEG) off[i] += add; }
}

// Bumps off[key] itself (no cursor): post-scatter, off[key] = exclusive END of
// segment key; readers use beg(k) = (k==0 ? 0 : off[k-1]).
// Packs src | rel<<20 | (dst&15)<<23.
__global__ void k_scatter(const int* __restrict__ src, const int* __restrict__ dst,
                          const int* __restrict__ et, int* __restrict__ off,
                          int* __restrict__ srcPk) {
  int e = blockIdx.x * 256 + threadIdx.x;
  if (e >= N_EDGES) return;
  int d = dst[e], r = et[e];
  int key = d * N_REL + r;
  int pos = atomicAdd(&off[key], 1);
  srcPk[pos] = src[e] | (r << 20) | ((d & 15) << 23);
}

__global__ __launch_bounds__(512)
void k_fused(const unsigned int* __restrict__ xb,
             const int* __restrict__ off, const int* __restrict__ srcPk,
             const __hip_bfloat16* __restrict__ WcatT,
             const float* __restrict__ bias, const float* __restrict__ alpha,
             float* __restrict__ out) {
  __shared__ __hip_bfloat16 B16[DT * BSTRIDE];   // 37,120 B
  __shared__ float invc[DT * N_REL];
  int tid = threadIdx.x;
  int wave = tid >> 6, lane = tid & 63;
  int dstBase = blockIdx.x * DT;
  int seg0 = dstBase * N_REL;

  // ---- pre-pass: zero agg region; root rows (bf16); per-segment 1/cnt ----
  for (int i = tid; i < DT * 128; i += 512) {          // [DT][1024] shorts, b128
    int row = i >> 7, c = i & 127;
    *reinterpret_cast<int4*>(&B16[row * BSTRIDE + c * 8]) = make_int4(0, 0, 0, 0);
  }
  for (int i = tid; i < DT * 64; i += 512) {           // root region k=1024..1151
    int row = i >> 6, c = i & 63;
    *reinterpret_cast<unsigned int*>(&B16[row * BSTRIDE + 1024 + c * 2]) =
        xb[(size_t)(dstBase + row) * 64 + c];
  }
  if (tid < DT * N_REL) {
    int sg = seg0 + tid;
    int beg = (sg == 0) ? 0 : off[sg - 1];
    int c = off[sg] - beg;
    invc[tid] = (c > 0) ? 1.0f / (float)c : 0.0f;
  }
  int segw = seg0 + wave * 16;                          // wave owns rows 2w,2w+1
  int ebeg = (segw == 0) ? 0 : off[segw - 1];
  int eend = off[segw + 15];
  __syncthreads();

  // ---- edge walk: 8-edge batches, register accumulation, flush per run ----
  float a0 = 0.f, a1 = 0.f;
  int curKey = -1;
  auto flush = [&]() {
    if (curKey >= 0) {
      int ld = curKey >> 3, r = curKey & 7;
      float iv = invc[(ld << 3) | r];
      __hip_bfloat16 b0 = __float2bfloat16(a0 * iv);
      __hip_bfloat16 b1 = __float2bfloat16(a1 * iv);
      unsigned int pk2 = (unsigned int)*(unsigned short*)&b0 |
                         ((unsigned int)*(unsigned short*)&b1 << 16);
      *reinterpret_cast<unsigned int*>(&B16[ld * BSTRIDE + r * CH + lane * 2]) = pk2;
    }
  };
  if (ebeg < eend) {
    int pkl = srcPk[min(ebeg + (lane & 7), eend - 1)];  // 8 descs, 32B coalesced
    for (int base = ebeg; base < eend; base += 8) {
      int pk[8];
#pragma unroll
      for (int j = 0; j < 8; ++j) pk[j] = __builtin_amdgcn_readlane(pkl, j);
      unsigned int u[8];
#pragma unroll
      for (int j = 0; j < 8; ++j)                       // 8 independent row gathers
        u[j] = xb[(size_t)(unsigned)(pk[j] & 0xFFFFF) * 64 + lane];
      int pkl_next = srcPk[min(base + 8 + (lane & 7), eend - 1)];  // pipeline ahead
#pragma unroll
      for (int j = 0; j < 8; ++j) {
        if (base + j < eend) {                          // wave-uniform guard
          int key = pk[j] >> 20;
          if (key != curKey) { flush(); curKey = key; a0 = 0.f; a1 = 0.f; }
          a0 += __uint_as_float(u[j] << 16);
          a1 += __uint_as_float(u[j] & 0xffff0000u);
        }
      }
      pkl = pkl_next;
    }
    flush();
  }
  __syncthreads();

  // ---- phase B: D[16x16] per wave over K=1152; wave w -> cols [16w,16w+16) ----
  int r16 = lane & 15, g = lane >> 4;
  f32x4 acc = {0.f, 0.f, 0.f, 0.f};
  const short* Wt = reinterpret_cast<const short*>(WcatT) + (size_t)(wave * 16 + r16) * KTOT;
  const short* Arow = reinterpret_cast<const short*>(B16) + r16 * BSTRIDE;
  for (int kk = 0; kk < KTOT / 32; ++kk) {
    int kb = kk * 32 + g * 8;
    bf16x8 af = *reinterpret_cast<const bf16x8*>(Arow + kb);
    bf16x8 bw = *reinterpret_cast<const bf16x8*>(Wt + kb);
    acc = __builtin_amdgcn_mfma_f32_16x16x32_bf16(af, bw, acc, 0, 0, 0);
  }

  int col = wave * 16 + r16;
  float bi = bias[col], al = alpha[col];
#pragma unroll
  for (int rg = 0; rg < 4; ++rg) {
    int row = g * 4 + rg;
    float v = acc[rg] + bi;
    v = (v >= 0.f) ? v : al * v;
    out[(size_t)(dstBase + row) * CH + col] = v;
  }
}

extern "C" void kernel_launch(void* const* d_in, const int* in_sizes, int n_in,
                              void* d_out, int out_size, void* d_ws, size_t ws_size,
                              hipStream_t stream) {
  const float* x     = (const float*)d_in[0];
  const int*   ei    = (const int*)d_in[1];
  const int*   etype = (const int*)d_in[2];
  const float* basis = (const float*)d_in[3];
  const float* comp  = (const float*)d_in[4];
  const float* root  = (const float*)d_in[5];
  const float* bias  = (const float*)d_in[6];
  const float* alpha = (const float*)d_in[7];
  const int* src = ei;
  const int* dst = ei + N_EDGES;
  float* out = (float*)d_out;

  char* ws = (char*)d_ws;
  size_t p = 0;
  auto alloc = [&](size_t bytes) {
    void* q = ws + p;
    p = (p + bytes + 255) & ~(size_t)255;
    return q;
  };
  __hip_bfloat16* WcatT = (__hip_bfloat16*)alloc((size_t)CH * KTOT * sizeof(__hip_bfloat16));
  int* off    = (int*)alloc((size_t)NSEG * sizeof(int));
  int* hist   = (int*)alloc((size_t)NSEG * sizeof(int));
  int* bsum   = (int*)alloc((size_t)NSCAN * sizeof(int));
  int* srcPk  = (int*)alloc((size_t)N_EDGES * sizeof(int));
  unsigned int* xb = (unsigned int*)alloc((size_t)N_NODES * CH / 2 * sizeof(unsigned int));

  hipMemsetAsync(hist, 0, (size_t)NSEG * sizeof(int), stream);
  k_build_w<<<(CH * KTOT + 255) / 256, 256, 0, stream>>>(basis, comp, root, WcatT);
  k_xbf16<<<(N_NODES * CH / 4 + 255) / 256, 256, 0, stream>>>(x, xb);
  k_hist<<<(N_EDGES + 255) / 256, 256, 0, stream>>>(dst, etype, hist);
  k_scan1<<<NSCAN, 256, 0, stream>>>(hist, off, bsum);
  k_scan2<<<1, 512, 0, stream>>>(bsum);
  k_scan3<<<NSCAN, 256, 0, stream>>>(off, bsum);
  k_scatter<<<(N_EDGES + 255) / 256, 256, 0, stream>>>(src, dst, etype, off, srcPk);
  k_fused<<<N_NODES / DT, 512, 0, stream>>>(xb, off, srcPk, WcatT, bias, alpha, out);
}

// Round 7
// 252.120 us; speedup vs baseline: 2.8985x; 1.0041x over previous
//
#include <hip/hip_runtime.h>
#include <hip/hip_bf16.h>

// RGCN layer, input-space aggregation, NO LDS atomics:
//   counting-sort edges by key = dst*8+etype (scatter bumps off[] itself; post-
//   scatter off[k] = segment END). Fused kernel: each wave owns 2 dst rows'
//   contiguous edge range; 16-edge batches (descs readlane'd to SGPRs -> saddr
//   gathers; 2-batch-ahead desc prefetch), REGISTER accumulation, flush once per
//   sorted run with a plain conflict-free ds_write. Then one MFMA GEMM
//   K = 8*128+128 vs [W_0;..;W_7;root] (W_r = comp@basis), bias+PReLU epilogue.

#define N_NODES 50000
#define N_EDGES 800000
#define N_REL   8
#define CH      128
#define KTOT    1152                       // 8*128 + 128 (root)
#define NSEG    (N_NODES * N_REL)          // 400000
#define DT      16                         // dst rows per fused block
#define SCAN_BLK 1024
#define NSCAN   ((NSEG + SCAN_BLK - 1) / SCAN_BLK)  // 391
#define BSTRIDE 1160                       // bf16 row stride; 2320B/16 = 145 ≡ 1 mod 8
#define WBLK    576                        // blocks for build_w part of k_prep

typedef __attribute__((ext_vector_type(8))) short bf16x8;
typedef __attribute__((ext_vector_type(4))) float f32x4;

// Merged: WcatT build (blocks [0,WBLK)) + x->bf16 convert (blocks [WBLK,..)).
__global__ void k_prep(const float* __restrict__ basis, const float* __restrict__ comp,
                       const float* __restrict__ root, __hip_bfloat16* __restrict__ WcatT,
                       const float* __restrict__ x, unsigned int* __restrict__ xb) {
  int b = blockIdx.x, tid = threadIdx.x;
  if (b < WBLK) {                          // WcatT[o][k], CH*KTOT = WBLK*256 exactly
    int idx = b * 256 + tid;
    int o = idx / KTOT, k = idx % KTOT;
    float v;
    if (k < N_REL * CH) {
      int r = k >> 7, i = k & (CH - 1);
      float acc = 0.f;
#pragma unroll
      for (int bb = 0; bb < 8; ++bb) acc += comp[r * 8 + bb] * basis[(bb * CH + i) * CH + o];
      v = acc;
    } else {
      v = root[(k - N_REL * CH) * CH + o];
    }
    WcatT[(size_t)o * KTOT + k] = __float2bfloat16(v);
  } else {                                 // xb: one thread = 4 channels
    int idx = (b - WBLK) * 256 + tid;      // N_NODES*CH/4 = 6250*256 exactly
    const float4 v = *reinterpret_cast<const float4*>(x + (size_t)idx * 4);
    __hip_bfloat16 h0 = __float2bfloat16(v.x), h1 = __float2bfloat16(v.y);
    __hip_bfloat16 h2 = __float2bfloat16(v.z), h3 = __float2bfloat16(v.w);
    xb[(size_t)idx * 2]     = *(unsigned short*)&h0 | ((unsigned int)*(unsigned short*)&h1 << 16);
    xb[(size_t)idx * 2 + 1] = *(unsigned short*)&h2 | ((unsigned int)*(unsigned short*)&h3 << 16);
  }
}

__global__ void k_hist(const int* __restrict__ dst, const int* __restrict__ et,
                       int* __restrict__ hist) {
  int e = blockIdx.x * 256 + threadIdx.x;
  if (e < N_EDGES) atomicAdd(&hist[dst[e] * N_REL + et[e]], 1);
}

__global__ void k_scan1(const int* __restrict__ hist, int* __restrict__ off,
                        int* __restrict__ bsum) {
  __shared__ int sd[256];
  int t = threadIdx.x, b = blockIdx.x;
  int base = b * SCAN_BLK + t * 4;
  int v[4]; int s = 0;
#pragma unroll
  for (int j = 0; j < 4; ++j) { int i = base + j; v[j] = (i < NSEG) ? hist[i] : 0; s += v[j]; }
  sd[t] = s; __syncthreads();
  for (int o = 1; o < 256; o <<= 1) {
    int add = (t >= o) ? sd[t - o] : 0; __syncthreads();
    sd[t] += add; __syncthreads();
  }
  int excl = sd[t] - s;
  int run = excl;
#pragma unroll
  for (int j = 0; j < 4; ++j) { int i = base + j; if (i < NSEG) off[i] = run; run += v[j]; }
  if (t == 255) bsum[b] = sd[255];
}

__global__ void k_scan2(int* __restrict__ bsum) {
  __shared__ int sd[512];
  int t = threadIdx.x;
  int v = (t < NSCAN) ? bsum[t] : 0;
  sd[t] = v; __syncthreads();
  for (int o = 1; o < 512; o <<= 1) {
    int add = (t >= o) ? sd[t - o] : 0; __syncthreads();
    sd[t] += add; __syncthreads();
  }
  int excl = (t == 0) ? 0 : sd[t - 1];
  if (t < NSCAN) bsum[t] = excl;
}

__global__ void k_scan3(int* __restrict__ off, const int* __restrict__ bsum) {
  int t = threadIdx.x, b = blockIdx.x;
  int add = bsum[b];
  int base = b * SCAN_BLK + t * 4;
#pragma unroll
  for (int j = 0; j < 4; ++j) { int i = base + j; if (i < NSEG) off[i] += add; }
}

// Bumps off[key] itself (no cursor): post-scatter, off[key] = exclusive END of
// segment key; readers use beg(k) = (k==0 ? 0 : off[k-1]).
// Packs src(16b) | rel<<16 | (dst&15)<<19.
__global__ void k_scatter(const int* __restrict__ src, const int* __restrict__ dst,
                          const int* __restrict__ et, int* __restrict__ off,
                          int* __restrict__ srcPk) {
  int e = blockIdx.x * 256 + threadIdx.x;
  if (e >= N_EDGES) return;
  int d = dst[e], r = et[e];
  int key = d * N_REL + r;
  int pos = atomicAdd(&off[key], 1);
  srcPk[pos] = src[e] | (r << 16) | ((d & 15) << 19);
}

__global__ __launch_bounds__(512)
void k_fused(const unsigned int* __restrict__ xb,
             const int* __restrict__ off, const int* __restrict__ srcPk,
             const __hip_bfloat16* __restrict__ WcatT,
             const float* __restrict__ bias, const float* __restrict__ alpha,
             float* __restrict__ out) {
  __shared__ __hip_bfloat16 B16[DT * BSTRIDE];   // 37,120 B
  __shared__ float invc[DT * N_REL];
  int tid = threadIdx.x;
  int wave = tid >> 6, lane = tid & 63;
  int dstBase = blockIdx.x * DT;
  int seg0 = dstBase * N_REL;

  // ---- pre-pass: zero agg region; root rows (bf16); per-segment 1/cnt ----
  for (int i = tid; i < DT * 128; i += 512) {          // [DT][1024] shorts, b128
    int row = i >> 7, c = i & 127;
    *reinterpret_cast<int4*>(&B16[row * BSTRIDE + c * 8]) = make_int4(0, 0, 0, 0);
  }
  for (int i = tid; i < DT * 64; i += 512) {           // root region k=1024..1151
    int row = i >> 6, c = i & 63;
    *reinterpret_cast<unsigned int*>(&B16[row * BSTRIDE + 1024 + c * 2]) =
        xb[(size_t)(dstBase + row) * 64 + c];
  }
  if (tid < DT * N_REL) {
    int sg = seg0 + tid;
    int beg = (sg == 0) ? 0 : off[sg - 1];
    int c = off[sg] - beg;
    invc[tid] = (c > 0) ? 1.0f / (float)c : 0.0f;
  }
  int segw = seg0 + wave * 16;                          // wave owns rows 2w,2w+1
  int ebeg = (segw == 0) ? 0 : off[segw - 1];
  int eend = off[segw + 15];
  __syncthreads();

  // ---- edge walk: 16-edge batches, 2-ahead desc prefetch, reg accumulation ----
  float a0 = 0.f, a1 = 0.f;
  int curKey = -1;
  auto flush = [&]() {
    if (curKey >= 0) {
      int ld = curKey >> 3, r = curKey & 7;
      float iv = invc[(ld << 3) | r];
      __hip_bfloat16 b0 = __float2bfloat16(a0 * iv);
      __hip_bfloat16 b1 = __float2bfloat16(a1 * iv);
      unsigned int pk2 = (unsigned int)*(unsigned short*)&b0 |
                         ((unsigned int)*(unsigned short*)&b1 << 16);
      *reinterpret_cast<unsigned int*>(&B16[ld * BSTRIDE + r * CH + lane * 2]) = pk2;
    }
  };
  if (ebeg < eend) {
    int nb = (eend - ebeg + 15) >> 4;
    int l16 = lane & 15;
    int pklA = srcPk[min(ebeg + l16, eend - 1)];            // batch 0 descs (64B)
    int pklB = srcPk[min(ebeg + 16 + l16, eend - 1)];       // batch 1 descs
    for (int b = 0; b < nb; ++b) {
      int base = ebeg + b * 16;
      int pk[16];
#pragma unroll
      for (int j = 0; j < 16; ++j) pk[j] = __builtin_amdgcn_readlane(pklA, j);
      unsigned int u[16];
#pragma unroll
      for (int j = 0; j < 16; ++j)                          // 16 independent saddr gathers
        u[j] = xb[(size_t)(unsigned)(pk[j] & 0xFFFF) * 64 + lane];
      int pklC = srcPk[min(base + 32 + l16, eend - 1)];     // batch b+2 descs
#pragma unroll
      for (int j = 0; j < 16; ++j) {
        if (base + j < eend) {                              // wave-uniform guard
          int key = pk[j] >> 16;
          if (key != curKey) { flush(); curKey = key; a0 = 0.f; a1 = 0.f; }
          a0 += __uint_as_float(u[j] << 16);
          a1 += __uint_as_float(u[j] & 0xffff0000u);
        }
      }
      pklA = pklB; pklB = pklC;
    }
    flush();
  }
  __syncthreads();

  // ---- phase B: D[16x16] per wave over K=1152; wave w -> cols [16w,16w+16) ----
  int r16 = lane & 15, g = lane >> 4;
  f32x4 acc = {0.f, 0.f, 0.f, 0.f};
  const short* Wt = reinterpret_cast<const short*>(WcatT) + (size_t)(wave * 16 + r16) * KTOT;
  const short* Arow = reinterpret_cast<const short*>(B16) + r16 * BSTRIDE;
  for (int kk = 0; kk < KTOT / 32; ++kk) {
    int kb = kk * 32 + g * 8;
    bf16x8 af = *reinterpret_cast<const bf16x8*>(Arow + kb);
    bf16x8 bw = *reinterpret_cast<const bf16x8*>(Wt + kb);
    acc = __builtin_amdgcn_mfma_f32_16x16x32_bf16(af, bw, acc, 0, 0, 0);
  }

  int col = wave * 16 + r16;
  float bi = bias[col], al = alpha[col];
#pragma unroll
  for (int rg = 0; rg < 4; ++rg) {
    int row = g * 4 + rg;
    float v = acc[rg] + bi;
    v = (v >= 0.f) ? v : al * v;
    out[(size_t)(dstBase + row) * CH + col] = v;
  }
}

extern "C" void kernel_launch(void* const* d_in, const int* in_sizes, int n_in,
                              void* d_out, int out_size, void* d_ws, size_t ws_size,
                              hipStream_t stream) {
  const float* x     = (const float*)d_in[0];
  const int*   ei    = (const int*)d_in[1];
  const int*   etype = (const int*)d_in[2];
  const float* basis = (const float*)d_in[3];
  const float* comp  = (const float*)d_in[4];
  const float* root  = (const float*)d_in[5];
  const float* bias  = (const float*)d_in[6];
  const float* alpha = (const float*)d_in[7];
  const int* src = ei;
  const int* dst = ei + N_EDGES;
  float* out = (float*)d_out;

  char* ws = (char*)d_ws;
  size_t p = 0;
  auto alloc = [&](size_t bytes) {
    void* q = ws + p;
    p = (p + bytes + 255) & ~(size_t)255;
    return q;
  };
  __hip_bfloat16* WcatT = (__hip_bfloat16*)alloc((size_t)CH * KTOT * sizeof(__hip_bfloat16));
  int* off    = (int*)alloc((size_t)NSEG * sizeof(int));
  int* hist   = (int*)alloc((size_t)NSEG * sizeof(int));
  int* bsum   = (int*)alloc((size_t)NSCAN * sizeof(int));
  int* srcPk  = (int*)alloc((size_t)N_EDGES * sizeof(int));
  unsigned int* xb = (unsigned int*)alloc((size_t)N_NODES * CH / 2 * sizeof(unsigned int));

  hipMemsetAsync(hist, 0, (size_t)NSEG * sizeof(int), stream);
  k_prep<<<WBLK + N_NODES * CH / 4 / 256, 256, 0, stream>>>(basis, comp, root, WcatT, x, xb);
  k_hist<<<(N_EDGES + 255) / 256, 256, 0, stream>>>(dst, etype, hist);
  k_scan1<<<NSCAN, 256, 0, stream>>>(hist, off, bsum);
  k_scan2<<<1, 512, 0, stream>>>(bsum);
  k_scan3<<<NSCAN, 256, 0, stream>>>(off, bsum);
  k_scatter<<<(N_EDGES + 255) / 256, 256, 0, stream>>>(src, dst, etype, off, srcPk);
  k_fused<<<N_NODES / DT, 512, 0, stream>>>(xb, off, srcPk, WcatT, bias, alpha, out);
}